// Round 2
// baseline (436.650 us; speedup 1.0000x reference)
//
#include <hip/hip_runtime.h>

#define B_   256
#define L_   200
#define D_   256
#define H_   8
#define DK_  32
#define IN_  64
#define HID_ 128
#define LAM_ 0.01f

using f32x4 = __attribute__((ext_vector_type(4))) float;
using bf16x8 = __attribute__((ext_vector_type(8))) short;

__device__ inline unsigned short bf16_rn(float f) {
  unsigned int u = __float_as_uint(f);
  return (unsigned short)((u + 0x7fffu + ((u >> 16) & 1u)) >> 16);
}

__device__ inline f32x4 mfma16(f32x4 c, bf16x8 a, bf16x8 b) {
  return __builtin_amdgcn_mfma_f32_16x16x32_bf16(a, b, c, 0, 0, 0);
}

// ---------------- cast x (f32 -> bf16), 8 elems/thread ----------------
__global__ __launch_bounds__(256) void cast_x_k(const float* __restrict__ x,
                                                unsigned short* __restrict__ xb) {
  long i = (long)blockIdx.x * 256 + threadIdx.x;  // 1,638,400 threads
  const float4* px = (const float4*)x;
  float4 a = px[2 * i], b = px[2 * i + 1];
  unsigned int w0 = bf16_rn(a.x) | ((unsigned int)bf16_rn(a.y) << 16);
  unsigned int w1 = bf16_rn(a.z) | ((unsigned int)bf16_rn(a.w) << 16);
  unsigned int w2 = bf16_rn(b.x) | ((unsigned int)bf16_rn(b.y) << 16);
  unsigned int w3 = bf16_rn(b.z) | ((unsigned int)bf16_rn(b.w) << 16);
  *(uint4*)(xb + 8 * i) = make_uint4(w0, w1, w2, w3);
}

// ---------------- hypernetwork h1, stored transposed h1t[j][b] ----------------
__global__ void hyper_h1(const float* __restrict__ ue, const float* __restrict__ fc1w,
                         const float* __restrict__ fc1b, float* __restrict__ h1t) {
  int b = blockIdx.x, j = threadIdx.x;
  __shared__ float us[IN_];
  if (j < IN_) us[j] = ue[b * IN_ + j];
  __syncthreads();
  float acc = fc1b[j];
#pragma unroll
  for (int i = 0; i < IN_; ++i) acc = fmaf(us[i], fc1w[i * HID_ + j], acc);
  h1t[j * B_ + b] = 1.f / (1.f + __expf(-acc));
}

// ---------------- transpose+cast Wk/Wv/Wo -> [n][k] bf16 ----------------
__global__ void prep_wt(const float* __restrict__ Wk, const float* __restrict__ Wv,
                        const float* __restrict__ Wo, unsigned short* __restrict__ wkT,
                        unsigned short* __restrict__ wvT, unsigned short* __restrict__ woT) {
  const float* W = blockIdx.y == 0 ? Wk : (blockIdx.y == 1 ? Wv : Wo);
  unsigned short* O = blockIdx.y == 0 ? wkT : (blockIdx.y == 1 ? wvT : woT);
  int n = blockIdx.x, k = threadIdx.x;
  O[n * D_ + k] = bf16_rn(W[k * D_ + n]);
}

// ---------------- w1[b][d][e] = LAM*(h1t[:,b].fc2w[:,de] + fc2b) + base_w ----------------
__global__ __launch_bounds__(256) void meta_w1(const float* __restrict__ h1t,
                                               const float* __restrict__ fc2w,
                                               const float* __restrict__ fc2b,
                                               const float* __restrict__ basew,
                                               unsigned short* __restrict__ w1) {
  int d = blockIdx.x, b0 = blockIdx.y * 32, e = threadIdx.x;
  float acc[32];
#pragma unroll
  for (int bb = 0; bb < 32; ++bb) acc[bb] = 0.f;
  const float* fw = fc2w + d * D_ + e;
  for (int j = 0; j < HID_; ++j) {
    float wv = fw[(long)j * (D_ * D_)];
    const float* hp = h1t + j * B_ + b0;  // wave-uniform -> s_load
#pragma unroll
    for (int bb = 0; bb < 32; ++bb) acc[bb] = fmaf(hp[bb], wv, acc[bb]);
  }
  float add = LAM_ * fc2b[d * D_ + e] + basew[d * D_ + e];
#pragma unroll
  for (int bb = 0; bb < 32; ++bb)
    w1[(long)(b0 + bb) * (D_ * D_) + d * D_ + e] = bf16_rn(LAM_ * acc[bb] + add);
}

// ---------------- transpose w1 -> w1t[b][e][d] (bf16) ----------------
__global__ __launch_bounds__(256) void transpose_w1(const unsigned short* __restrict__ w1,
                                                    unsigned short* __restrict__ w1t) {
  __shared__ unsigned short t[32][36];
  long b = blockIdx.y;
  int d0 = (blockIdx.x >> 3) * 32, e0 = (blockIdx.x & 7) * 32;
  int r = threadIdx.x >> 3, c4 = (threadIdx.x & 7) * 4;
  const unsigned short* src = w1 + b * (D_ * D_);
  uint2 vv = *(const uint2*)(src + (d0 + r) * D_ + e0 + c4);
  *(uint2*)(&t[r][c4]) = vv;
  __syncthreads();
  unsigned short o0 = t[c4 + 0][r], o1 = t[c4 + 1][r], o2 = t[c4 + 2][r], o3 = t[c4 + 3][r];
  unsigned int lo = o0 | ((unsigned int)o1 << 16), hi = o2 | ((unsigned int)o3 << 16);
  *(uint2*)(w1t + b * (D_ * D_) + (e0 + r) * D_ + d0 + c4) = make_uint2(lo, hi);
}

// ---------------- GEMM C[b] = A[b] @ Wt[b]^T + bias ----------------
// A: bf16 [.., K=256] row-major; Wt: bf16 [n][k]; tile 64x64, 4 waves, BK=32.
template <int OUT_BF16>
__global__ __launch_bounds__(256) void gemm_bt(const unsigned short* __restrict__ A,
                                               const unsigned short* __restrict__ Wt,
                                               const float* __restrict__ bias,
                                               void* __restrict__ Cout, int Mvalid,
                                               long bsA, long bsW, long bsC) {
  __shared__ unsigned short ldsA[64][40];  // pad 40 to spread row banks
  __shared__ unsigned short ldsB[64][40];
  int b = blockIdx.z;
  int row0 = blockIdx.x * 64, n0 = blockIdx.y * 64;
  int tid = threadIdx.x, lane = tid & 63, w = tid >> 6;
  int wr = w >> 1, wc = w & 1, c = lane & 15, g = lane >> 4;
  const unsigned short* Ab = A + (long)b * bsA;
  const unsigned short* Wb = Wt + (long)b * bsW;
  int sr = tid >> 2, sk = (tid & 3) * 8;
  long arow = row0 + sr;
  if (arow >= Mvalid) arow = Mvalid - 1;
  f32x4 zero = {0.f, 0.f, 0.f, 0.f};
  f32x4 acc[2][2];
#pragma unroll
  for (int mi = 0; mi < 2; ++mi)
#pragma unroll
    for (int ni = 0; ni < 2; ++ni) acc[mi][ni] = zero;

  for (int kt = 0; kt < 8; ++kt) {
    int k0 = kt * 32;
    uint4 av = *(const uint4*)(Ab + arow * D_ + k0 + sk);
    uint4 bv = *(const uint4*)(Wb + (long)(n0 + sr) * D_ + k0 + sk);
    __syncthreads();
    *(uint4*)(&ldsA[sr][sk]) = av;
    *(uint4*)(&ldsB[sr][sk]) = bv;
    __syncthreads();
    bf16x8 af[2], bfr[2];
#pragma unroll
    for (int mi = 0; mi < 2; ++mi) af[mi] = *(const bf16x8*)(&ldsA[wr * 32 + mi * 16 + c][g * 8]);
#pragma unroll
    for (int ni = 0; ni < 2; ++ni) bfr[ni] = *(const bf16x8*)(&ldsB[wc * 32 + ni * 16 + c][g * 8]);
#pragma unroll
    for (int mi = 0; mi < 2; ++mi)
#pragma unroll
      for (int ni = 0; ni < 2; ++ni) acc[mi][ni] = mfma16(acc[mi][ni], af[mi], bfr[ni]);
  }
#pragma unroll
  for (int mi = 0; mi < 2; ++mi)
#pragma unroll
    for (int ni = 0; ni < 2; ++ni) {
      int col = n0 + wc * 32 + ni * 16 + c;
      float bi = bias[col];
#pragma unroll
      for (int j = 0; j < 4; ++j) {
        int row = row0 + wr * 32 + mi * 16 + g * 4 + j;
        if (row < Mvalid) {
          float val = acc[mi][ni][j] + bi;
          long off = (long)b * bsC + (long)row * D_ + col;
          if (OUT_BF16)
            ((unsigned short*)Cout)[off] = bf16_rn(val);
          else
            ((float*)Cout)[off] = val;
        }
      }
    }
}

// ---------------- fused causal attention per (b, h, 64-row q tile) ----------------
__global__ __launch_bounds__(256) void attn_k(const unsigned short* __restrict__ q,
                                              const unsigned short* __restrict__ k,
                                              const unsigned short* __restrict__ v,
                                              unsigned short* __restrict__ o) {
  __shared__ unsigned short ldsK[224][40];   // [m][d], padded
  __shared__ unsigned short ldsVT[32][232];  // [d][m]
  __shared__ unsigned short ldsP[64][232];   // [l][m] bf16 probs
  int b = blockIdx.z, h = blockIdx.y, q0 = blockIdx.x * 64;
  int tid = threadIdx.x, lane = tid & 63, w = tid >> 6, c = lane & 15, g = lane >> 4;
  long base = ((long)b * L_) * D_ + h * DK_;

  for (int idx = tid; idx < 224 * 4; idx += 256) {
    int m = idx >> 2, pp = idx & 3;
    int mc = m < L_ ? m : L_ - 1;
    uint4 kv = *(const uint4*)(k + base + (long)mc * D_ + pp * 8);
    *(uint4*)(&ldsK[m][pp * 8]) = kv;
    uint4 vv = *(const uint4*)(v + base + (long)mc * D_ + pp * 8);
    const unsigned short* vs = (const unsigned short*)&vv;
#pragma unroll
    for (int dd = 0; dd < 8; ++dd) ldsVT[pp * 8 + dd][m] = vs[dd];
  }
  int ql = q0 + w * 16 + c;
  if (ql >= L_) ql = L_ - 1;
  bf16x8 qf = *(const bf16x8*)(q + base + (long)ql * D_ + g * 8);
  __syncthreads();

  f32x4 zero = {0.f, 0.f, 0.f, 0.f};
  f32x4 s[14];
#pragma unroll
  for (int mf = 0; mf < 14; ++mf) {
    bf16x8 kf = *(const bf16x8*)(&ldsK[mf * 16 + c][g * 8]);
    s[mf] = mfma16(zero, qf, kf);
  }
  const float scale = 0.17677669529663687f;  // 1/sqrt(32)
  int lg = q0 + w * 16 + g * 4;              // + j = this lane's query rows
#pragma unroll
  for (int mf = 0; mf < 14; ++mf) {
    int m = mf * 16 + c;
#pragma unroll
    for (int j = 0; j < 4; ++j) {
      bool val = (m <= lg + j) && (m < L_);
      s[mf][j] = val ? s[mf][j] * scale : -1e9f;
    }
  }
  float mx[4], sm[4];
#pragma unroll
  for (int j = 0; j < 4; ++j) {
    float m0 = s[0][j];
#pragma unroll
    for (int mf = 1; mf < 14; ++mf) m0 = fmaxf(m0, s[mf][j]);
    m0 = fmaxf(m0, __shfl_xor(m0, 1));
    m0 = fmaxf(m0, __shfl_xor(m0, 2));
    m0 = fmaxf(m0, __shfl_xor(m0, 4));
    m0 = fmaxf(m0, __shfl_xor(m0, 8));
    mx[j] = m0;
  }
#pragma unroll
  for (int j = 0; j < 4; ++j) {
    float ss = 0.f;
#pragma unroll
    for (int mf = 0; mf < 14; ++mf) {
      float p = __expf(s[mf][j] - mx[j]);
      s[mf][j] = p;
      ss += p;
    }
    ss += __shfl_xor(ss, 1);
    ss += __shfl_xor(ss, 2);
    ss += __shfl_xor(ss, 4);
    ss += __shfl_xor(ss, 8);
    sm[j] = ss;
  }
#pragma unroll
  for (int mf = 0; mf < 14; ++mf)
#pragma unroll
    for (int j = 0; j < 4; ++j) ldsP[w * 16 + g * 4 + j][mf * 16 + c] = bf16_rn(s[mf][j]);
  __syncthreads();

  f32x4 oa[2];
  oa[0] = zero;
  oa[1] = zero;
#pragma unroll
  for (int kb = 0; kb < 7; ++kb) {
    bf16x8 pf = *(const bf16x8*)(&ldsP[w * 16 + c][kb * 32 + g * 8]);
#pragma unroll
    for (int nf = 0; nf < 2; ++nf) {
      bf16x8 vf = *(const bf16x8*)(&ldsVT[nf * 16 + c][kb * 32 + g * 8]);
      oa[nf] = mfma16(oa[nf], pf, vf);
    }
  }
  float inv[4];
#pragma unroll
  for (int j = 0; j < 4; ++j) inv[j] = 1.f / sm[j];
#pragma unroll
  for (int nf = 0; nf < 2; ++nf)
#pragma unroll
    for (int j = 0; j < 4; ++j) {
      int l = q0 + w * 16 + g * 4 + j;
      if (l < L_) o[base + (long)l * D_ + nf * 16 + c] = bf16_rn(oa[nf][j] * inv[j]);
    }
}

extern "C" void kernel_launch(void* const* d_in, const int* in_sizes, int n_in,
                              void* d_out, int out_size, void* d_ws, size_t ws_size,
                              hipStream_t stream) {
  const float* x = (const float*)d_in[0];
  const float* ue = (const float*)d_in[1];
  const float* fc1w = (const float*)d_in[2];
  const float* fc1b = (const float*)d_in[3];
  const float* fc2w = (const float*)d_in[4];
  const float* fc2b = (const float*)d_in[5];
  const float* bw = (const float*)d_in[6];
  const float* bq = (const float*)d_in[7];
  const float* Wk = (const float*)d_in[8];
  const float* bk = (const float*)d_in[9];
  const float* Wv = (const float*)d_in[10];
  const float* bv = (const float*)d_in[11];
  const float* Wo = (const float*)d_in[12];
  const float* bo = (const float*)d_in[13];

  char* ws = (char*)d_ws;
  unsigned short* xb = (unsigned short*)(ws + 0);           // 26,214,400 B (x bf16; later o)
  unsigned short* qb = (unsigned short*)(ws + 26214400);    // 26,214,400 B
  unsigned short* w1 = (unsigned short*)(ws + 52428800);    // 33,554,432 B (w1; later k)
  unsigned short* w1t = (unsigned short*)(ws + 85983232);   // 33,554,432 B (w1t; later v)
  float* h1t = (float*)(ws + 119537664);                    // 131,072 B
  unsigned short* wkT = (unsigned short*)(ws + 119668736);  // 131,072 B
  unsigned short* wvT = (unsigned short*)(ws + 119799808);  // 131,072 B
  unsigned short* woT = (unsigned short*)(ws + 119930880);  // 131,072 B
  unsigned short* kb_ = w1;   // aliases: w1 dead after transpose
  unsigned short* vb = w1t;   // w1t dead after q GEMM
  unsigned short* ob = xb;    // x dead after v GEMM

  cast_x_k<<<6400, 256, 0, stream>>>(x, xb);
  hyper_h1<<<256, 128, 0, stream>>>(ue, fc1w, fc1b, h1t);
  prep_wt<<<dim3(256, 3), 256, 0, stream>>>(Wk, Wv, Wo, wkT, wvT, woT);
  meta_w1<<<dim3(256, 8), 256, 0, stream>>>(h1t, fc2w, fc2b, bw, w1);
  transpose_w1<<<dim3(64, 256), 256, 0, stream>>>(w1, w1t);
  // q = x @ w1 + b_q   (per-batch weight)
  gemm_bt<1><<<dim3(4, 4, 256), 256, 0, stream>>>(xb, w1t, bq, qb, L_, (long)L_ * D_,
                                                  (long)D_ * D_, (long)L_ * D_);
  // k = x @ Wk + bk ; v = x @ Wv + bv   (flat M = B*L)
  gemm_bt<1><<<dim3(800, 4, 1), 256, 0, stream>>>(xb, wkT, bk, kb_, B_ * L_, 0L, 0L, 0L);
  gemm_bt<1><<<dim3(800, 4, 1), 256, 0, stream>>>(xb, wvT, bv, vb, B_ * L_, 0L, 0L, 0L);
  // fused causal attention -> o (bf16)
  attn_k<<<dim3(4, H_, B_), 256, 0, stream>>>(qb, kb_, vb, ob);
  // out = o @ Wo + bo (f32 -> d_out)
  gemm_bt<0><<<dim3(800, 4, 1), 256, 0, stream>>>(ob, woT, bo, d_out, B_ * L_, 0L, 0L, 0L);
}